// Round 3
// baseline (260.519 us; speedup 1.0000x reference)
//
#include <hip/hip_runtime.h>
#include <math.h>

#define H_FM 200
#define W_FM 304
#define C_FM 256
#define NPIX (H_FM * W_FM)           // 60800
#define CROP 14
#define PH 7
#define NPOS 49                       // 7*7
#define NSAMP (NPOS * 4)              // 196 (position, sample) pairs
#define SLABS 16
#define SLAB_C 16                     // channels per slab
#define SLAB_ELEMS (NPIX * SLAB_C)    // 972800 floats = 3.89 MB dense per slab
#define SPIXB (SLAB_C * 4)            // 64 B per pixel within a slab
#define PIXB (C_FM * 4)               // 1024 B per pixel original layout

#define SLAB_BYTES ((size_t)SLABS * SLAB_ELEMS * sizeof(float))   // 62,259,200

typedef float floatx4 __attribute__((ext_vector_type(4)));

// ---------------------------------------------------------------------------
// Geometry table: computed ONCE per (ROI, sample) instead of once per
// (ROI, slab, sample) — kills the 16x redundant divides/floors/clamps that
// were ~1/3 of the pool kernel's VALU issue.
//   odTab[g] = { byte_off(tap00), dxB | dyB<<16 }
//   wTab[g]  = { w00, w01, w10, w11 }  (zeroed when sample invalid)
// ---------------------------------------------------------------------------
__global__ __launch_bounds__(256) void geom_kernel(
    const float* __restrict__ proposals,   // [N,4] (x1,y1,x2,y2) image coords
    const int*   __restrict__ image_shape, // [2] (H_img, W_img)
    uint2*       __restrict__ odTab,       // [N*NSAMP]
    float4*      __restrict__ wTab,        // [N*NSAMP]
    int N)
{
    const int g = blockIdx.x * 256 + threadIdx.x;
    if (g >= N * NSAMP) return;

    const int n = g / NSAMP;
    const int t = g - n * NSAMP;
    const int s  = t & 3;
    const int p  = t >> 2;
    const int py = p / PH;
    const int px = p - py * PH;
    const int a  = s >> 1;          // y sub-offset in 2x2 window
    const int b  = s & 1;           // x sub-offset

    const float himg = (float)image_shape[0];
    const float wimg = (float)image_shape[1];

    const float bx1 = proposals[n * 4 + 0] / wimg;
    const float by1 = proposals[n * 4 + 1] / himg;
    const float bx2 = proposals[n * 4 + 2] / wimg;
    const float by2 = proposals[n * 4 + 3] / himg;

    const float Hm1 = (float)(H_FM - 1);
    const float Wm1 = (float)(W_FM - 1);

    // matches reference: ys = y1*(H-1) + i * ((y2-y1)*(H-1)/(crop-1))
    const float ystep = (by2 - by1) * Hm1 / (float)(CROP - 1);
    const float xstep = (bx2 - bx1) * Wm1 / (float)(CROP - 1);
    const float ys = by1 * Hm1 + (float)(2 * py + a) * ystep;
    const float xs = bx1 * Wm1 + (float)(2 * px + b) * xstep;

    const float y0f = floorf(ys);
    const float x0f = floorf(xs);
    const float ly  = ys - y0f;
    const float lx  = xs - x0f;

    int y0 = min(max((int)y0f, 0), H_FM - 1);
    int x0 = min(max((int)x0f, 0), W_FM - 1);
    const int dy = min(y0 + 1, H_FM - 1) - y0;   // 0 or 1
    const int dx = min(x0 + 1, W_FM - 1) - x0;   // 0 or 1

    const bool valid = (ys >= 0.0f) && (ys <= Hm1) &&
                       (xs >= 0.0f) && (xs <= Wm1);
    const float vf   = valid ? 1.0f : 0.0f;
    const float omlx = 1.0f - lx;
    const float omly = 1.0f - ly;

    float4 w;
    w.x = omlx * omly * vf;   // w00
    w.y = lx   * omly * vf;   // w01
    w.z = omlx * ly   * vf;   // w10
    w.w = lx   * ly   * vf;   // w11

    uint2 od;
    od.x = (uint32_t)(y0 * W_FM + x0) * SPIXB;
    od.y = (uint32_t)(dx * SPIXB) | ((uint32_t)(dy * W_FM * SPIXB) << 16);

    odTab[g] = od;
    wTab[g]  = w;
}

// ---------------------------------------------------------------------------
// Repack [H,W,256] -> 16 dense slabs [NPIX][16], LDS-tiled so both sides are
// dense (unchanged from R2, ~17us).
// ---------------------------------------------------------------------------
#define TP 16  // pixels per block
__global__ __launch_bounds__(256) void repack_kernel(
    const float* __restrict__ fm,      // [NPIX, 256]
    float*       __restrict__ slabbed) // [16][NPIX][16]
{
    __shared__ float lds[TP][C_FM + 4];
    const int tid = threadIdx.x;
    const int p0  = blockIdx.x * TP;

    const float4* src = (const float4*)(fm + (size_t)p0 * C_FM);
    #pragma unroll
    for (int i = 0; i < 4; ++i) {
        const int idx = i * 256 + tid;
        const float4 v = src[idx];
        const int pix = idx >> 6;
        const int c4  = idx & 63;
        *(float4*)&lds[pix][c4 * 4] = v;
    }
    __syncthreads();

    const int s = tid >> 4;
    const int j = tid & 15;
    float* dst = slabbed + (size_t)s * SLAB_ELEMS + (size_t)p0 * SLAB_C;
    #pragma unroll
    for (int k = 0; k < 4; ++k) {
        const int m   = k * 16 + j;
        const int pix = m >> 2;
        const int cq  = m & 3;
        const float4 v = *(const float4*)&lds[pix][s * SLAB_C + cq * 4];
        *(float4*)(dst + m * 4) = v;
    }
}

// ---------------------------------------------------------------------------
// Pool kernel (table version). Block = (ROI n, slab), XCD-pinned so each XCD
// streams one dense 3.9MB L2-resident slab. No LDS, no __syncthreads:
// geometry comes from the precomputed table (L1/L2-hot, 4.7KB per ROI).
// Hot loop: ALL 16 tap loads issued before any FMA (arrays fully unrolled ->
// registers; VGPR rises deliberately so one position pays ~1 L2 latency, not
// 4 sequential ones), then 4-FMA weighted bilinear + pairwise fmax tree.
// ---------------------------------------------------------------------------
__global__ __launch_bounds__(256) void roi_pool_tab_kernel(
    const float* __restrict__ slabbed,     // [16][NPIX][16]
    const uint2* __restrict__ odTab,       // [N*NSAMP]
    const float4* __restrict__ wTab,       // [N*NSAMP]
    float*       __restrict__ out,         // [N,7,7,256]
    int N)
{
    const int bid   = blockIdx.x;
    const int xcd   = bid & 7;
    const int jj    = bid >> 3;        // 0 .. 2N-1
    const int phase = jj / N;          // 0 or 1
    const int n     = jj - phase * N;  // ROI index
    const int slab  = phase * 8 + xcd; // 0..15

    const int tid  = threadIdx.x;
    const int wave = tid >> 6;
    const int lane = tid & 63;
    const int p    = wave * 16 + (lane >> 2);   // output position 0..63
    const int q    = lane & 3;                  // channel quad within slab
    const int pa   = min(p, NPOS - 1);          // wave 3 partly idle

    const char* base = (const char*)slabbed + (size_t)slab * SLAB_BYTES / SLABS;
    const uint32_t qB = (uint32_t)q * 16u;
    const int tbase = n * NSAMP + pa * 4;

    // ---- fetch geometry (4 lanes share each entry; HW dedups segments) ----
    uint2  od[4];
    float4 wv[4];
    #pragma unroll
    for (int s = 0; s < 4; ++s) {
        od[s] = odTab[tbase + s];
        wv[s] = wTab[tbase + s];
    }

    // ---- issue all 16 tap loads ----
    float4 t00[4], t01[4], t10[4], t11[4];
    #pragma unroll
    for (int s = 0; s < 4; ++s) {
        const uint32_t o00 = od[s].x + qB;
        const uint32_t dxB = od[s].y & 0xffffu;
        const uint32_t dyB = od[s].y >> 16;
        t00[s] = *(const float4*)(base + o00);
        t01[s] = *(const float4*)(base + o00 + dxB);
        t10[s] = *(const float4*)(base + o00 + dyB);
        t11[s] = *(const float4*)(base + o00 + dxB + dyB);
    }

    // ---- bilinear (weighted sum, matches ref to ulp via fmaf chain) ----
    float4 v[4];
    #pragma unroll
    for (int s = 0; s < 4; ++s) {
        v[s].x = fmaf(t00[s].x, wv[s].x, fmaf(t01[s].x, wv[s].y, fmaf(t10[s].x, wv[s].z, t11[s].x * wv[s].w)));
        v[s].y = fmaf(t00[s].y, wv[s].x, fmaf(t01[s].y, wv[s].y, fmaf(t10[s].y, wv[s].z, t11[s].y * wv[s].w)));
        v[s].z = fmaf(t00[s].z, wv[s].x, fmaf(t01[s].z, wv[s].y, fmaf(t10[s].z, wv[s].z, t11[s].z * wv[s].w)));
        v[s].w = fmaf(t00[s].w, wv[s].x, fmaf(t01[s].w, wv[s].y, fmaf(t10[s].w, wv[s].z, t11[s].w * wv[s].w)));
    }

    // ---- 2x2 max (exact regardless of order) ----
    if (p < NPOS) {
        floatx4 m;
        m.x = fmaxf(fmaxf(v[0].x, v[1].x), fmaxf(v[2].x, v[3].x));
        m.y = fmaxf(fmaxf(v[0].y, v[1].y), fmaxf(v[2].y, v[3].y));
        m.z = fmaxf(fmaxf(v[0].z, v[1].z), fmaxf(v[2].z, v[3].z));
        m.w = fmaxf(fmaxf(v[0].w, v[1].w), fmaxf(v[2].w, v[3].w));
        // non-temporal: keep the 98MB output stream from evicting the slab
        __builtin_nontemporal_store(m,
            (floatx4*)(out + ((size_t)n * NPOS + p) * C_FM + slab * SLAB_C + q * 4));
    }
}

// ---------------------------------------------------------------------------
// Fallback 1 (ws fits slabs but not tables): R2 slab kernel, inline geometry.
// ---------------------------------------------------------------------------
__global__ __launch_bounds__(256) void roi_pool_slab_kernel(
    const float* __restrict__ slabbed,
    const float* __restrict__ proposals,
    const int*   __restrict__ image_shape,
    float*       __restrict__ out,
    int N)
{
    __shared__ uint2  gOD[224];
    __shared__ float4 gW[224];

    const int bid   = blockIdx.x;
    const int xcd   = bid & 7;
    const int jj    = bid >> 3;
    const int phase = jj / N;
    const int n     = jj - phase * N;
    const int slab  = phase * 8 + xcd;

    const int tid = threadIdx.x;

    if (tid < NSAMP) {
        const int s  = tid & 3;
        const int p  = tid >> 2;
        const int py = p / PH;
        const int px = p - py * PH;
        const int a  = s >> 1;
        const int b  = s & 1;

        const float himg = (float)image_shape[0];
        const float wimg = (float)image_shape[1];
        const float bx1 = proposals[n * 4 + 0] / wimg;
        const float by1 = proposals[n * 4 + 1] / himg;
        const float bx2 = proposals[n * 4 + 2] / wimg;
        const float by2 = proposals[n * 4 + 3] / himg;

        const float Hm1 = (float)(H_FM - 1);
        const float Wm1 = (float)(W_FM - 1);
        const float ystep = (by2 - by1) * Hm1 / (float)(CROP - 1);
        const float xstep = (bx2 - bx1) * Wm1 / (float)(CROP - 1);
        const float ys = by1 * Hm1 + (float)(2 * py + a) * ystep;
        const float xs = bx1 * Wm1 + (float)(2 * px + b) * xstep;

        const float y0f = floorf(ys);
        const float x0f = floorf(xs);
        const float ly  = ys - y0f;
        const float lx  = xs - x0f;
        int y0 = min(max((int)y0f, 0), H_FM - 1);
        int x0 = min(max((int)x0f, 0), W_FM - 1);
        const int dy = min(y0 + 1, H_FM - 1) - y0;
        const int dx = min(x0 + 1, W_FM - 1) - x0;
        const bool valid = (ys >= 0.0f) && (ys <= Hm1) &&
                           (xs >= 0.0f) && (xs <= Wm1);
        const float vf   = valid ? 1.0f : 0.0f;
        const float omlx = 1.0f - lx;
        const float omly = 1.0f - ly;

        float4 w;
        w.x = omlx * omly * vf;
        w.y = lx   * omly * vf;
        w.z = omlx * ly   * vf;
        w.w = lx   * ly   * vf;

        uint2 od;
        od.x = (uint32_t)(y0 * W_FM + x0) * SPIXB;
        od.y = (uint32_t)(dx * SPIXB) | ((uint32_t)(dy * W_FM * SPIXB) << 16);

        const int esk = tid + (tid >> 3);
        gOD[esk] = od;
        gW[esk]  = w;
    }
    __syncthreads();

    const int wave = tid >> 6;
    const int lane = tid & 63;
    const int p    = wave * 16 + (lane >> 2);
    const int q    = lane & 3;
    const int pa   = min(p, NPOS - 1);

    const char* base = (const char*)slabbed + (size_t)slab * (SLAB_ELEMS * sizeof(float));
    const uint32_t qB = (uint32_t)q * 16u;

    float4 m;
    #pragma unroll
    for (int s = 0; s < 4; ++s) {
        const int e   = pa * 4 + s;
        const int esk = e + (e >> 3);
        const uint2  od = gOD[esk];
        const float4 w  = gW[esk];
        const uint32_t o00 = od.x + qB;
        const uint32_t dxB = od.y & 0xffffu;
        const uint32_t dyB = od.y >> 16;
        const float4 t00 = *(const float4*)(base + o00);
        const float4 t01 = *(const float4*)(base + o00 + dxB);
        const float4 t10 = *(const float4*)(base + o00 + dyB);
        const float4 t11 = *(const float4*)(base + o00 + dxB + dyB);
        float4 v;
        v.x = fmaf(t00.x, w.x, fmaf(t01.x, w.y, fmaf(t10.x, w.z, t11.x * w.w)));
        v.y = fmaf(t00.y, w.x, fmaf(t01.y, w.y, fmaf(t10.y, w.z, t11.y * w.w)));
        v.z = fmaf(t00.z, w.x, fmaf(t01.z, w.y, fmaf(t10.z, w.z, t11.z * w.w)));
        v.w = fmaf(t00.w, w.x, fmaf(t01.w, w.y, fmaf(t10.w, w.z, t11.w * w.w)));
        if (s == 0) { m = v; }
        else {
            m.x = fmaxf(m.x, v.x); m.y = fmaxf(m.y, v.y);
            m.z = fmaxf(m.z, v.z); m.w = fmaxf(m.w, v.w);
        }
    }

    if (p < NPOS) {
        floatx4 mv;
        mv.x = m.x; mv.y = m.y; mv.z = m.z; mv.w = m.w;
        __builtin_nontemporal_store(mv,
            (floatx4*)(out + ((size_t)n * NPOS + p) * C_FM + slab * SLAB_C + q * 4));
    }
}

// ---------------------------------------------------------------------------
// Fallback 2 (no workspace): direct all-channel kernel.
// ---------------------------------------------------------------------------
__global__ __launch_bounds__(256) void roi_pool_direct_kernel(
    const float* __restrict__ fm,
    const float* __restrict__ proposals,
    const int*   __restrict__ image_shape,
    float*       __restrict__ out,
    int N)
{
    __shared__ uint4  gO[NSAMP];
    __shared__ float4 gWf[NSAMP];

    const int n   = blockIdx.x;
    const int tid = threadIdx.x;

    if (tid < NSAMP) {
        const int s  = tid & 3;
        const int p  = tid >> 2;
        const int py = p / PH;
        const int px = p - py * PH;
        const int a  = s >> 1;
        const int b  = s & 1;

        const float himg = (float)image_shape[0];
        const float wimg = (float)image_shape[1];
        const float bx1 = proposals[n * 4 + 0] / wimg;
        const float by1 = proposals[n * 4 + 1] / himg;
        const float bx2 = proposals[n * 4 + 2] / wimg;
        const float by2 = proposals[n * 4 + 3] / himg;

        const float Hm1 = (float)(H_FM - 1);
        const float Wm1 = (float)(W_FM - 1);
        const float ystep = (by2 - by1) * Hm1 / (float)(CROP - 1);
        const float xstep = (bx2 - bx1) * Wm1 / (float)(CROP - 1);
        const float ys = by1 * Hm1 + (float)(2 * py + a) * ystep;
        const float xs = bx1 * Wm1 + (float)(2 * px + b) * xstep;

        const float y0f = floorf(ys);
        const float x0f = floorf(xs);
        const float ly  = ys - y0f;
        const float lx  = xs - x0f;
        int y0 = min(max((int)y0f, 0), H_FM - 1);
        int x0 = min(max((int)x0f, 0), W_FM - 1);
        const int dy = min(y0 + 1, H_FM - 1) - y0;
        const int dx = min(x0 + 1, W_FM - 1) - x0;
        const bool valid = (ys >= 0.0f) && (ys <= Hm1) &&
                           (xs >= 0.0f) && (xs <= Wm1);
        const float vf   = valid ? 1.0f : 0.0f;
        const float omlx = 1.0f - lx;
        const float omly = 1.0f - ly;

        float4 w;
        w.x = omlx * omly * vf;
        w.y = lx   * omly * vf;
        w.z = omlx * ly   * vf;
        w.w = lx   * ly   * vf;

        uint4 o;
        o.x = (uint32_t)(y0 * W_FM + x0) * PIXB;
        o.y = (uint32_t)dx * PIXB;
        o.z = (uint32_t)(dy * W_FM) * PIXB;
        o.w = 0u;
        gO[tid]  = o;
        gWf[tid] = w;
    }
    __syncthreads();

    const int wave = tid >> 6;
    const int lane = tid & 63;
    const uint32_t laneB = (uint32_t)lane * 16u;
    const char* fmB  = (const char*)fm;
    char*       outB = (char*)out + (size_t)n * (NPOS * PIXB);

    const int pbeg = (wave * NPOS) >> 2;
    const int pend = ((wave + 1) * NPOS) >> 2;

    for (int p = pbeg; p < pend; ++p) {
        float4 m;
        #pragma unroll
        for (int s = 0; s < 4; ++s) {
            const uint4  o = gO[p * 4 + s];
            const float4 w = gWf[p * 4 + s];
            const uint32_t o00 = o.x + laneB;
            const float4 t00 = *(const float4*)(fmB + o00);
            const float4 t01 = *(const float4*)(fmB + o00 + o.y);
            const float4 t10 = *(const float4*)(fmB + o00 + o.z);
            const float4 t11 = *(const float4*)(fmB + o00 + o.y + o.z);
            float4 v;
            v.x = fmaf(t00.x, w.x, fmaf(t01.x, w.y, fmaf(t10.x, w.z, t11.x * w.w)));
            v.y = fmaf(t00.y, w.x, fmaf(t01.y, w.y, fmaf(t10.y, w.z, t11.y * w.w)));
            v.z = fmaf(t00.z, w.x, fmaf(t01.z, w.y, fmaf(t10.z, w.z, t11.z * w.w)));
            v.w = fmaf(t00.w, w.x, fmaf(t01.w, w.y, fmaf(t10.w, w.z, t11.w * w.w)));
            if (s == 0) { m = v; }
            else {
                m.x = fmaxf(m.x, v.x); m.y = fmaxf(m.y, v.y);
                m.z = fmaxf(m.z, v.z); m.w = fmaxf(m.w, v.w);
            }
        }
        floatx4 mv;
        mv.x = m.x; mv.y = m.y; mv.z = m.z; mv.w = m.w;
        __builtin_nontemporal_store(mv,
            (floatx4*)(outB + (uint32_t)p * PIXB + laneB));
    }
}

extern "C" void kernel_launch(void* const* d_in, const int* in_sizes, int n_in,
                              void* d_out, int out_size, void* d_ws, size_t ws_size,
                              hipStream_t stream) {
    (void)n_in; (void)out_size;

    const float* fm        = (const float*)d_in[0];  // [1,200,304,256] f32
    const float* proposals = (const float*)d_in[1];  // [N,4] f32
    const int*   imshape   = (const int*)d_in[2];    // [2] i32
    float* out = (float*)d_out;                      // [N,7,7,256] f32

    const int N = in_sizes[1] / 4;                   // 2000
    const int nsamp_total = N * NSAMP;               // 392000

    const size_t od_bytes   = (size_t)nsamp_total * sizeof(uint2);   // 3,136,000
    const size_t w_bytes    = (size_t)nsamp_total * sizeof(float4);  // 6,272,000
    const size_t need_slab  = SLAB_BYTES;                            // 62,259,200
    const size_t need_full  = need_slab + od_bytes + w_bytes;        // ~71.7 MB

    if (ws_size >= need_full) {
        uint2*  odTab = (uint2*)((char*)d_ws + need_slab);
        float4* wTab  = (float4*)((char*)d_ws + need_slab + od_bytes);
        geom_kernel<<<(nsamp_total + 255) / 256, 256, 0, stream>>>(
            proposals, imshape, odTab, wTab, N);
        repack_kernel<<<NPIX / TP, 256, 0, stream>>>(fm, (float*)d_ws);
        roi_pool_tab_kernel<<<SLABS * N, 256, 0, stream>>>(
            (const float*)d_ws, odTab, wTab, out, N);
    } else if (ws_size >= need_slab) {
        repack_kernel<<<NPIX / TP, 256, 0, stream>>>(fm, (float*)d_ws);
        roi_pool_slab_kernel<<<SLABS * N, 256, 0, stream>>>(
            (const float*)d_ws, proposals, imshape, out, N);
    } else {
        roi_pool_direct_kernel<<<N, 256, 0, stream>>>(
            fm, proposals, imshape, out, N);
    }
}

// Round 4
// 246.379 us; speedup vs baseline: 1.0574x; 1.0574x over previous
//
#include <hip/hip_runtime.h>
#include <math.h>

#define H_FM 200
#define W_FM 304
#define C_FM 256
#define NPIX (H_FM * W_FM)           // 60800
#define CROP 14
#define PH 7
#define NPOS 49                       // 7*7
#define NSAMP (NPOS * 4)              // 196
#define SLABS 16
#define SLAB_C 16                     // channels per slab
#define SLAB_ELEMS (NPIX * SLAB_C)    // 972800 floats = 3.89 MB dense per slab
#define SPIXB (SLAB_C * 4)            // 64 B per pixel within a slab
#define PIXB (C_FM * 4)               // 1024 B per pixel original layout
#define GEOM_PER_ROI 28               // 14 row entries + 14 col entries

#define SLAB_BYTES ((size_t)SLABS * SLAB_ELEMS * sizeof(float))   // 62,259,200

typedef float floatx4 __attribute__((ext_vector_type(4)));

// ---------------------------------------------------------------------------
// Factored geometry: 28 entries per ROI (14 crop rows + 14 crop cols),
// 16 B each -> 448 B/ROI, 896 KB total. This is the R3 table idea with the
// footprint cut 10x so it L2-coexists with the 3.9MB slab (R3's 9.4MB table
// thrashed the 4MB per-XCD L2 -> 134MB FETCH).
//   row entry i: { yOffB = y0*W*64, bits((1-ly)*vy), bits(ly*vy), dyB }
//   col entry j: { xOffB = x0*64,   bits((1-lx)*vx), bits(lx*vx), dxB }
// Sample weights reassemble as products: w00 = wt*wl etc.; validity is folded
// into the factors (any invalid axis zeroes all 4 products, matching the
// reference's where(valid, val, 0)).
// ---------------------------------------------------------------------------
__global__ __launch_bounds__(256) void geom_kernel(
    const float* __restrict__ proposals,   // [N,4] (x1,y1,x2,y2) image coords
    const int*   __restrict__ image_shape, // [2] (H_img, W_img)
    uint4*       __restrict__ geomTab,     // [N*28]
    int N)
{
    const int g = blockIdx.x * 256 + threadIdx.x;
    if (g >= N * GEOM_PER_ROI) return;

    const int n = g / GEOM_PER_ROI;
    const int e = g - n * GEOM_PER_ROI;

    const float himg = (float)image_shape[0];
    const float wimg = (float)image_shape[1];

    const float bx1 = proposals[n * 4 + 0] / wimg;
    const float by1 = proposals[n * 4 + 1] / himg;
    const float bx2 = proposals[n * 4 + 2] / wimg;
    const float by2 = proposals[n * 4 + 3] / himg;

    const float Hm1 = (float)(H_FM - 1);
    const float Wm1 = (float)(W_FM - 1);

    // matches reference: ys = y1*(H-1) + i * ((y2-y1)*(H-1)/(crop-1))
    uint4 out;
    if (e < CROP) {
        const int i = e;
        const float ystep = (by2 - by1) * Hm1 / (float)(CROP - 1);
        const float ys    = by1 * Hm1 + (float)i * ystep;
        const float y0f   = floorf(ys);
        const float ly    = ys - y0f;
        int y0 = min(max((int)y0f, 0), H_FM - 1);
        const int dy = min(y0 + 1, H_FM - 1) - y0;           // 0 or 1
        const bool vy = (ys >= 0.0f) && (ys <= Hm1);
        const float vf = vy ? 1.0f : 0.0f;
        out.x = (uint32_t)(y0 * W_FM) * SPIXB;
        out.y = __float_as_uint((1.0f - ly) * vf);           // top-row factor
        out.z = __float_as_uint(ly * vf);                    // bottom-row factor
        out.w = (uint32_t)(dy * W_FM) * SPIXB;
    } else {
        const int j = e - CROP;
        const float xstep = (bx2 - bx1) * Wm1 / (float)(CROP - 1);
        const float xs    = bx1 * Wm1 + (float)j * xstep;
        const float x0f   = floorf(xs);
        const float lx    = xs - x0f;
        int x0 = min(max((int)x0f, 0), W_FM - 1);
        const int dx = min(x0 + 1, W_FM - 1) - x0;           // 0 or 1
        const bool vx = (xs >= 0.0f) && (xs <= Wm1);
        const float vf = vx ? 1.0f : 0.0f;
        out.x = (uint32_t)x0 * SPIXB;
        out.y = __float_as_uint((1.0f - lx) * vf);           // left-col factor
        out.z = __float_as_uint(lx * vf);                    // right-col factor
        out.w = (uint32_t)dx * SPIXB;
    }
    geomTab[g] = out;
}

// ---------------------------------------------------------------------------
// Repack [H,W,256] -> 16 dense slabs [NPIX][16], LDS-tiled so both sides are
// dense (unchanged, ~17us).
// ---------------------------------------------------------------------------
#define TP 16  // pixels per block
__global__ __launch_bounds__(256) void repack_kernel(
    const float* __restrict__ fm,      // [NPIX, 256]
    float*       __restrict__ slabbed) // [16][NPIX][16]
{
    __shared__ float lds[TP][C_FM + 4];
    const int tid = threadIdx.x;
    const int p0  = blockIdx.x * TP;

    const float4* src = (const float4*)(fm + (size_t)p0 * C_FM);
    #pragma unroll
    for (int i = 0; i < 4; ++i) {
        const int idx = i * 256 + tid;
        const float4 v = src[idx];
        const int pix = idx >> 6;
        const int c4  = idx & 63;
        *(float4*)&lds[pix][c4 * 4] = v;
    }
    __syncthreads();

    const int s = tid >> 4;
    const int j = tid & 15;
    float* dst = slabbed + (size_t)s * SLAB_ELEMS + (size_t)p0 * SLAB_C;
    #pragma unroll
    for (int k = 0; k < 4; ++k) {
        const int m   = k * 16 + j;
        const int pix = m >> 2;
        const int cq  = m & 3;
        const float4 v = *(const float4*)&lds[pix][s * SLAB_C + cq * 4];
        *(float4*)(dst + m * 4) = v;
    }
}

// ---------------------------------------------------------------------------
// Pool kernel (factored-table version). Block = (ROI n, slab), XCD-pinned so
// each XCD streams one dense L2-resident slab. No LDS, no __syncthreads.
// Per lane: 4 table loads (row0,row1,col0,col1 entries of its position;
// 448B/ROI -> L1-hot), then 4 samples x {2 adds, 4 weight muls, 4 tap loads,
// 16 FMA}, in-register fmax tree, one NT store.
// ---------------------------------------------------------------------------
__global__ __launch_bounds__(256) void roi_pool_fac_kernel(
    const float* __restrict__ slabbed,     // [16][NPIX][16]
    const uint4* __restrict__ geomTab,     // [N*28]
    float*       __restrict__ out,         // [N,7,7,256]
    int N)
{
    const int bid   = blockIdx.x;
    const int xcd   = bid & 7;
    const int jj    = bid >> 3;        // 0 .. 2N-1
    const int phase = jj / N;          // 0 or 1
    const int n     = jj - phase * N;  // ROI index
    const int slab  = phase * 8 + xcd; // 0..15

    const int tid  = threadIdx.x;
    const int wave = tid >> 6;
    const int lane = tid & 63;
    const int p    = wave * 16 + (lane >> 2);   // output position 0..63
    const int q    = lane & 3;                  // channel quad within slab
    const int pa   = min(p, NPOS - 1);          // wave 3 partly idle
    const int py   = pa / PH;
    const int px   = pa - py * PH;

    const char* base = (const char*)slabbed + (size_t)slab * (SLAB_ELEMS * sizeof(float));
    const uint32_t qB = (uint32_t)q * 16u;

    const uint4* gt = geomTab + n * GEOM_PER_ROI;
    const uint4 yg0 = gt[2 * py];
    const uint4 yg1 = gt[2 * py + 1];
    const uint4 xg0 = gt[CROP + 2 * px];
    const uint4 xg1 = gt[CROP + 2 * px + 1];

    float4 m;
    #pragma unroll
    for (int s = 0; s < 4; ++s) {
        const uint4 yg = (s & 2) ? yg1 : yg0;   // a = s>>1 (compile-time select)
        const uint4 xg = (s & 1) ? xg1 : xg0;   // b = s&1

        const uint32_t o00 = yg.x + xg.x + qB;
        const uint32_t dxB = xg.w;
        const uint32_t dyB = yg.w;

        const float wt = __uint_as_float(yg.y);   // (1-ly)*vy
        const float wb = __uint_as_float(yg.z);   // ly*vy
        const float wl = __uint_as_float(xg.y);   // (1-lx)*vx
        const float wr = __uint_as_float(xg.z);   // lx*vx

        const float w00 = wt * wl;
        const float w01 = wt * wr;
        const float w10 = wb * wl;
        const float w11 = wb * wr;

        const float4 t00 = *(const float4*)(base + o00);
        const float4 t01 = *(const float4*)(base + o00 + dxB);
        const float4 t10 = *(const float4*)(base + o00 + dyB);
        const float4 t11 = *(const float4*)(base + o00 + dxB + dyB);

        float4 v;
        v.x = fmaf(t00.x, w00, fmaf(t01.x, w01, fmaf(t10.x, w10, t11.x * w11)));
        v.y = fmaf(t00.y, w00, fmaf(t01.y, w01, fmaf(t10.y, w10, t11.y * w11)));
        v.z = fmaf(t00.z, w00, fmaf(t01.z, w01, fmaf(t10.z, w10, t11.z * w11)));
        v.w = fmaf(t00.w, w00, fmaf(t01.w, w01, fmaf(t10.w, w10, t11.w * w11)));

        if (s == 0) { m = v; }
        else {
            m.x = fmaxf(m.x, v.x); m.y = fmaxf(m.y, v.y);
            m.z = fmaxf(m.z, v.z); m.w = fmaxf(m.w, v.w);
        }
    }

    if (p < NPOS) {
        floatx4 mv;
        mv.x = m.x; mv.y = m.y; mv.z = m.z; mv.w = m.w;
        // non-temporal: keep the 98MB output stream from evicting the slab
        __builtin_nontemporal_store(mv,
            (floatx4*)(out + ((size_t)n * NPOS + p) * C_FM + slab * SLAB_C + q * 4));
    }
}

// ---------------------------------------------------------------------------
// Fallback 1 (ws fits slabs only): R2 slab kernel, inline geometry.
// ---------------------------------------------------------------------------
__global__ __launch_bounds__(256) void roi_pool_slab_kernel(
    const float* __restrict__ slabbed,
    const float* __restrict__ proposals,
    const int*   __restrict__ image_shape,
    float*       __restrict__ out,
    int N)
{
    __shared__ uint2  gOD[224];
    __shared__ float4 gW[224];

    const int bid   = blockIdx.x;
    const int xcd   = bid & 7;
    const int jj    = bid >> 3;
    const int phase = jj / N;
    const int n     = jj - phase * N;
    const int slab  = phase * 8 + xcd;

    const int tid = threadIdx.x;

    if (tid < NSAMP) {
        const int s  = tid & 3;
        const int p  = tid >> 2;
        const int py = p / PH;
        const int px = p - py * PH;
        const int a  = s >> 1;
        const int b  = s & 1;

        const float himg = (float)image_shape[0];
        const float wimg = (float)image_shape[1];
        const float bx1 = proposals[n * 4 + 0] / wimg;
        const float by1 = proposals[n * 4 + 1] / himg;
        const float bx2 = proposals[n * 4 + 2] / wimg;
        const float by2 = proposals[n * 4 + 3] / himg;

        const float Hm1 = (float)(H_FM - 1);
        const float Wm1 = (float)(W_FM - 1);
        const float ystep = (by2 - by1) * Hm1 / (float)(CROP - 1);
        const float xstep = (bx2 - bx1) * Wm1 / (float)(CROP - 1);
        const float ys = by1 * Hm1 + (float)(2 * py + a) * ystep;
        const float xs = bx1 * Wm1 + (float)(2 * px + b) * xstep;

        const float y0f = floorf(ys);
        const float x0f = floorf(xs);
        const float ly  = ys - y0f;
        const float lx  = xs - x0f;
        int y0 = min(max((int)y0f, 0), H_FM - 1);
        int x0 = min(max((int)x0f, 0), W_FM - 1);
        const int dy = min(y0 + 1, H_FM - 1) - y0;
        const int dx = min(x0 + 1, W_FM - 1) - x0;
        const bool valid = (ys >= 0.0f) && (ys <= Hm1) &&
                           (xs >= 0.0f) && (xs <= Wm1);
        const float vf   = valid ? 1.0f : 0.0f;
        const float omlx = 1.0f - lx;
        const float omly = 1.0f - ly;

        float4 w;
        w.x = omlx * omly * vf;
        w.y = lx   * omly * vf;
        w.z = omlx * ly   * vf;
        w.w = lx   * ly   * vf;

        uint2 od;
        od.x = (uint32_t)(y0 * W_FM + x0) * SPIXB;
        od.y = (uint32_t)(dx * SPIXB) | ((uint32_t)(dy * W_FM * SPIXB) << 16);

        const int esk = tid + (tid >> 3);
        gOD[esk] = od;
        gW[esk]  = w;
    }
    __syncthreads();

    const int wave = tid >> 6;
    const int lane = tid & 63;
    const int p    = wave * 16 + (lane >> 2);
    const int q    = lane & 3;
    const int pa   = min(p, NPOS - 1);

    const char* base = (const char*)slabbed + (size_t)slab * (SLAB_ELEMS * sizeof(float));
    const uint32_t qB = (uint32_t)q * 16u;

    float4 m;
    #pragma unroll
    for (int s = 0; s < 4; ++s) {
        const int e   = pa * 4 + s;
        const int esk = e + (e >> 3);
        const uint2  od = gOD[esk];
        const float4 w  = gW[esk];
        const uint32_t o00 = od.x + qB;
        const uint32_t dxB = od.y & 0xffffu;
        const uint32_t dyB = od.y >> 16;
        const float4 t00 = *(const float4*)(base + o00);
        const float4 t01 = *(const float4*)(base + o00 + dxB);
        const float4 t10 = *(const float4*)(base + o00 + dyB);
        const float4 t11 = *(const float4*)(base + o00 + dxB + dyB);
        float4 v;
        v.x = fmaf(t00.x, w.x, fmaf(t01.x, w.y, fmaf(t10.x, w.z, t11.x * w.w)));
        v.y = fmaf(t00.y, w.x, fmaf(t01.y, w.y, fmaf(t10.y, w.z, t11.y * w.w)));
        v.z = fmaf(t00.z, w.x, fmaf(t01.z, w.y, fmaf(t10.z, w.z, t11.z * w.w)));
        v.w = fmaf(t00.w, w.x, fmaf(t01.w, w.y, fmaf(t10.w, w.z, t11.w * w.w)));
        if (s == 0) { m = v; }
        else {
            m.x = fmaxf(m.x, v.x); m.y = fmaxf(m.y, v.y);
            m.z = fmaxf(m.z, v.z); m.w = fmaxf(m.w, v.w);
        }
    }

    if (p < NPOS) {
        floatx4 mv;
        mv.x = m.x; mv.y = m.y; mv.z = m.z; mv.w = m.w;
        __builtin_nontemporal_store(mv,
            (floatx4*)(out + ((size_t)n * NPOS + p) * C_FM + slab * SLAB_C + q * 4));
    }
}

// ---------------------------------------------------------------------------
// Fallback 2 (no workspace): direct all-channel kernel.
// ---------------------------------------------------------------------------
__global__ __launch_bounds__(256) void roi_pool_direct_kernel(
    const float* __restrict__ fm,
    const float* __restrict__ proposals,
    const int*   __restrict__ image_shape,
    float*       __restrict__ out,
    int N)
{
    __shared__ uint4  gO[NSAMP];
    __shared__ float4 gWf[NSAMP];

    const int n   = blockIdx.x;
    const int tid = threadIdx.x;

    if (tid < NSAMP) {
        const int s  = tid & 3;
        const int p  = tid >> 2;
        const int py = p / PH;
        const int px = p - py * PH;
        const int a  = s >> 1;
        const int b  = s & 1;

        const float himg = (float)image_shape[0];
        const float wimg = (float)image_shape[1];
        const float bx1 = proposals[n * 4 + 0] / wimg;
        const float by1 = proposals[n * 4 + 1] / himg;
        const float bx2 = proposals[n * 4 + 2] / wimg;
        const float by2 = proposals[n * 4 + 3] / himg;

        const float Hm1 = (float)(H_FM - 1);
        const float Wm1 = (float)(W_FM - 1);
        const float ystep = (by2 - by1) * Hm1 / (float)(CROP - 1);
        const float xstep = (bx2 - bx1) * Wm1 / (float)(CROP - 1);
        const float ys = by1 * Hm1 + (float)(2 * py + a) * ystep;
        const float xs = bx1 * Wm1 + (float)(2 * px + b) * xstep;

        const float y0f = floorf(ys);
        const float x0f = floorf(xs);
        const float ly  = ys - y0f;
        const float lx  = xs - x0f;
        int y0 = min(max((int)y0f, 0), H_FM - 1);
        int x0 = min(max((int)x0f, 0), W_FM - 1);
        const int dy = min(y0 + 1, H_FM - 1) - y0;
        const int dx = min(x0 + 1, W_FM - 1) - x0;
        const bool valid = (ys >= 0.0f) && (ys <= Hm1) &&
                           (xs >= 0.0f) && (xs <= Wm1);
        const float vf   = valid ? 1.0f : 0.0f;
        const float omlx = 1.0f - lx;
        const float omly = 1.0f - ly;

        float4 w;
        w.x = omlx * omly * vf;
        w.y = lx   * omly * vf;
        w.z = omlx * ly   * vf;
        w.w = lx   * ly   * vf;

        uint4 o;
        o.x = (uint32_t)(y0 * W_FM + x0) * PIXB;
        o.y = (uint32_t)dx * PIXB;
        o.z = (uint32_t)(dy * W_FM) * PIXB;
        o.w = 0u;
        gO[tid]  = o;
        gWf[tid] = w;
    }
    __syncthreads();

    const int wave = tid >> 6;
    const int lane = tid & 63;
    const uint32_t laneB = (uint32_t)lane * 16u;
    const char* fmB  = (const char*)fm;
    char*       outB = (char*)out + (size_t)n * (NPOS * PIXB);

    const int pbeg = (wave * NPOS) >> 2;
    const int pend = ((wave + 1) * NPOS) >> 2;

    for (int p = pbeg; p < pend; ++p) {
        float4 m;
        #pragma unroll
        for (int s = 0; s < 4; ++s) {
            const uint4  o = gO[p * 4 + s];
            const float4 w = gWf[p * 4 + s];
            const uint32_t o00 = o.x + laneB;
            const float4 t00 = *(const float4*)(fmB + o00);
            const float4 t01 = *(const float4*)(fmB + o00 + o.y);
            const float4 t10 = *(const float4*)(fmB + o00 + o.z);
            const float4 t11 = *(const float4*)(fmB + o00 + o.y + o.z);
            float4 v;
            v.x = fmaf(t00.x, w.x, fmaf(t01.x, w.y, fmaf(t10.x, w.z, t11.x * w.w)));
            v.y = fmaf(t00.y, w.x, fmaf(t01.y, w.y, fmaf(t10.y, w.z, t11.y * w.w)));
            v.z = fmaf(t00.z, w.x, fmaf(t01.z, w.y, fmaf(t10.z, w.z, t11.z * w.w)));
            v.w = fmaf(t00.w, w.x, fmaf(t01.w, w.y, fmaf(t10.w, w.z, t11.w * w.w)));
            if (s == 0) { m = v; }
            else {
                m.x = fmaxf(m.x, v.x); m.y = fmaxf(m.y, v.y);
                m.z = fmaxf(m.z, v.z); m.w = fmaxf(m.w, v.w);
            }
        }
        floatx4 mv;
        mv.x = m.x; mv.y = m.y; mv.z = m.z; mv.w = m.w;
        __builtin_nontemporal_store(mv,
            (floatx4*)(outB + (uint32_t)p * PIXB + laneB));
    }
}

extern "C" void kernel_launch(void* const* d_in, const int* in_sizes, int n_in,
                              void* d_out, int out_size, void* d_ws, size_t ws_size,
                              hipStream_t stream) {
    (void)n_in; (void)out_size;

    const float* fm        = (const float*)d_in[0];  // [1,200,304,256] f32
    const float* proposals = (const float*)d_in[1];  // [N,4] f32
    const int*   imshape   = (const int*)d_in[2];    // [2] i32
    float* out = (float*)d_out;                      // [N,7,7,256] f32

    const int N = in_sizes[1] / 4;                   // 2000
    const int ngeom = N * GEOM_PER_ROI;              // 56000

    const size_t geom_bytes = (size_t)ngeom * sizeof(uint4);         // 896,000
    const size_t need_slab  = SLAB_BYTES;                            // 62,259,200
    const size_t need_full  = need_slab + geom_bytes;                // ~63.2 MB

    if (ws_size >= need_full) {
        uint4* geomTab = (uint4*)((char*)d_ws + need_slab);
        geom_kernel<<<(ngeom + 255) / 256, 256, 0, stream>>>(
            proposals, imshape, geomTab, N);
        repack_kernel<<<NPIX / TP, 256, 0, stream>>>(fm, (float*)d_ws);
        roi_pool_fac_kernel<<<SLABS * N, 256, 0, stream>>>(
            (const float*)d_ws, geomTab, out, N);
    } else if (ws_size >= need_slab) {
        repack_kernel<<<NPIX / TP, 256, 0, stream>>>(fm, (float*)d_ws);
        roi_pool_slab_kernel<<<SLABS * N, 256, 0, stream>>>(
            (const float*)d_ws, proposals, imshape, out, N);
    } else {
        roi_pool_direct_kernel<<<N, 256, 0, stream>>>(
            fm, proposals, imshape, out, N);
    }
}

// Round 5
// 212.170 us; speedup vs baseline: 1.2279x; 1.1612x over previous
//
#include <hip/hip_runtime.h>
#include <math.h>

#define H_FM 200
#define W_FM 304
#define C_FM 256
#define NPIX (H_FM * W_FM)           // 60800
#define CROP 14
#define PH 7
#define NPOS 49                       // 7*7
#define NSAMP (NPOS * 4)              // 196
#define SLABS 16
#define SLAB_C 16                     // channels per slab
#define SLAB_ELEMS (NPIX * SLAB_C)    // 972800 floats = 3.89 MB dense per slab
#define SPIXB (SLAB_C * 4)            // 64 B per pixel within a slab
#define PIXB (C_FM * 4)               // 1024 B per pixel original layout
#define GEOM_PER_ROI 28               // 14 row entries + 14 col entries

#define SLAB_BYTES ((size_t)SLABS * SLAB_ELEMS * sizeof(float))   // 62,259,200

typedef float floatx4 __attribute__((ext_vector_type(4)));

// ---------------------------------------------------------------------------
// Repack [H,W,256] -> 16 dense slabs [NPIX][16], LDS-tiled so both sides are
// dense (unchanged, ~17us).
// ---------------------------------------------------------------------------
#define TP 16  // pixels per block
__global__ __launch_bounds__(256) void repack_kernel(
    const float* __restrict__ fm,      // [NPIX, 256]
    float*       __restrict__ slabbed) // [16][NPIX][16]
{
    __shared__ float lds[TP][C_FM + 4];
    const int tid = threadIdx.x;
    const int p0  = blockIdx.x * TP;

    const float4* src = (const float4*)(fm + (size_t)p0 * C_FM);
    #pragma unroll
    for (int i = 0; i < 4; ++i) {
        const int idx = i * 256 + tid;
        const float4 v = src[idx];
        const int pix = idx >> 6;
        const int c4  = idx & 63;
        *(float4*)&lds[pix][c4 * 4] = v;
    }
    __syncthreads();

    const int s = tid >> 4;
    const int j = tid & 15;
    float* dst = slabbed + (size_t)s * SLAB_ELEMS + (size_t)p0 * SLAB_C;
    #pragma unroll
    for (int k = 0; k < 4; ++k) {
        const int m   = k * 16 + j;
        const int pix = m >> 2;
        const int cq  = m & 3;
        const float4 v = *(const float4*)&lds[pix][s * SLAB_C + cq * 4];
        *(float4*)(dst + m * 4) = v;
    }
}

// ---------------------------------------------------------------------------
// Fused pool kernel. Block = (ROI n, slab), XCD-pinned so each XCD streams one
// dense 3.9MB L2-resident slab.
//
// Phase 1 (threads 0..27): compute the FACTORED geometry (14 row + 14 col
// entries) straight into LDS — no geom_kernel dispatch, no global table, and
// tap addresses wait only on an LDS read, not on dependent global loads.
//   row i: { yOffB, bits((1-ly)*vy), bits(ly*vy), dyB }
//   col j: { xOffB, bits((1-lx)*vx), bits(lx*vx), dxB }
// Validity folded into the factors (zero product == reference where(valid)).
//
// Phase 2: lane = pos16*4 + quad. ALL 16 offsets computed, then ALL 16 tap
// loads issued as one independent batch (the R3/R4 lesson: at VGPR=36 the
// compiler serialized them ~500cy each -> latency-bound at 109us).
// __launch_bounds__(256,2) lifts the VGPR cap to 128 (~116 used) while
// keeping 4 waves/SIMD — 16-deep MLP per lane.
// ---------------------------------------------------------------------------
__global__ __launch_bounds__(256, 2) void roi_pool_fused_kernel(
    const float* __restrict__ slabbed,     // [16][NPIX][16]
    const float* __restrict__ proposals,   // [N,4] (x1,y1,x2,y2) image coords
    const int*   __restrict__ image_shape, // [2] (H_img, W_img)
    float*       __restrict__ out,         // [N,7,7,256]
    int N)
{
    __shared__ uint4 gLds[GEOM_PER_ROI];

    const int bid   = blockIdx.x;
    const int xcd   = bid & 7;
    const int jj    = bid >> 3;        // 0 .. 2N-1
    const int phase = jj / N;          // 0 or 1
    const int n     = jj - phase * N;  // ROI index
    const int slab  = phase * 8 + xcd; // 0..15

    const int tid = threadIdx.x;

    if (tid < GEOM_PER_ROI) {
        const int e = tid;

        const float himg = (float)image_shape[0];
        const float wimg = (float)image_shape[1];

        const float bx1 = proposals[n * 4 + 0] / wimg;
        const float by1 = proposals[n * 4 + 1] / himg;
        const float bx2 = proposals[n * 4 + 2] / wimg;
        const float by2 = proposals[n * 4 + 3] / himg;

        const float Hm1 = (float)(H_FM - 1);
        const float Wm1 = (float)(W_FM - 1);

        uint4 ge;
        if (e < CROP) {
            const int i = e;
            // matches reference: ys = y1*(H-1) + i*((y2-y1)*(H-1)/(crop-1))
            const float ystep = (by2 - by1) * Hm1 / (float)(CROP - 1);
            const float ys    = by1 * Hm1 + (float)i * ystep;
            const float y0f   = floorf(ys);
            const float ly    = ys - y0f;
            int y0 = min(max((int)y0f, 0), H_FM - 1);
            const int dy = min(y0 + 1, H_FM - 1) - y0;       // 0 or 1
            const bool vy = (ys >= 0.0f) && (ys <= Hm1);
            const float vf = vy ? 1.0f : 0.0f;
            ge.x = (uint32_t)(y0 * W_FM) * SPIXB;
            ge.y = __float_as_uint((1.0f - ly) * vf);        // top factor
            ge.z = __float_as_uint(ly * vf);                 // bottom factor
            ge.w = (uint32_t)(dy * W_FM) * SPIXB;
        } else {
            const int j = e - CROP;
            const float xstep = (bx2 - bx1) * Wm1 / (float)(CROP - 1);
            const float xs    = bx1 * Wm1 + (float)j * xstep;
            const float x0f   = floorf(xs);
            const float lx    = xs - x0f;
            int x0 = min(max((int)x0f, 0), W_FM - 1);
            const int dx = min(x0 + 1, W_FM - 1) - x0;       // 0 or 1
            const bool vx = (xs >= 0.0f) && (xs <= Wm1);
            const float vf = vx ? 1.0f : 0.0f;
            ge.x = (uint32_t)x0 * SPIXB;
            ge.y = __float_as_uint((1.0f - lx) * vf);        // left factor
            ge.z = __float_as_uint(lx * vf);                 // right factor
            ge.w = (uint32_t)dx * SPIXB;
        }
        gLds[e] = ge;
    }
    __syncthreads();

    const int wave = tid >> 6;
    const int lane = tid & 63;
    const int p    = wave * 16 + (lane >> 2);   // output position 0..63
    const int q    = lane & 3;                  // channel quad within slab
    const int pa   = min(p, NPOS - 1);          // wave 3 partly idle (dup pos 48)
    const int py   = pa / PH;
    const int px   = pa - py * PH;

    const char* base = (const char*)slabbed + (size_t)slab * (SLAB_ELEMS * sizeof(float));
    const uint32_t qB = (uint32_t)q * 16u;

    // geometry for this position's 2x2 sample window (LDS broadcast reads)
    const uint4 yg0 = gLds[2 * py];
    const uint4 yg1 = gLds[2 * py + 1];
    const uint4 xg0 = gLds[CROP + 2 * px];
    const uint4 xg1 = gLds[CROP + 2 * px + 1];

    // ---- all 16 offsets + all 16 weights (pure VALU, no memory deps) ----
#define GEOM_SAMPLE(s, YG, XG) \
    const uint32_t o00_##s = YG.x + XG.x + qB;              \
    const uint32_t o01_##s = o00_##s + XG.w;                \
    const uint32_t o10_##s = o00_##s + YG.w;                \
    const uint32_t o11_##s = o10_##s + XG.w;                \
    const float wt_##s = __uint_as_float(YG.y);             \
    const float wb_##s = __uint_as_float(YG.z);             \
    const float wl_##s = __uint_as_float(XG.y);             \
    const float wr_##s = __uint_as_float(XG.z);             \
    const float w00_##s = wt_##s * wl_##s;                  \
    const float w01_##s = wt_##s * wr_##s;                  \
    const float w10_##s = wb_##s * wl_##s;                  \
    const float w11_##s = wb_##s * wr_##s;

    GEOM_SAMPLE(0, yg0, xg0)
    GEOM_SAMPLE(1, yg0, xg1)
    GEOM_SAMPLE(2, yg1, xg0)
    GEOM_SAMPLE(3, yg1, xg1)
#undef GEOM_SAMPLE

    // ---- 16 independent tap loads: issue the whole batch before any use ----
    const float4 t00_0 = *(const float4*)(base + o00_0);
    const float4 t01_0 = *(const float4*)(base + o01_0);
    const float4 t10_0 = *(const float4*)(base + o10_0);
    const float4 t11_0 = *(const float4*)(base + o11_0);
    const float4 t00_1 = *(const float4*)(base + o00_1);
    const float4 t01_1 = *(const float4*)(base + o01_1);
    const float4 t10_1 = *(const float4*)(base + o10_1);
    const float4 t11_1 = *(const float4*)(base + o11_1);
    const float4 t00_2 = *(const float4*)(base + o00_2);
    const float4 t01_2 = *(const float4*)(base + o01_2);
    const float4 t10_2 = *(const float4*)(base + o10_2);
    const float4 t11_2 = *(const float4*)(base + o11_2);
    const float4 t00_3 = *(const float4*)(base + o00_3);
    const float4 t01_3 = *(const float4*)(base + o01_3);
    const float4 t10_3 = *(const float4*)(base + o10_3);
    const float4 t11_3 = *(const float4*)(base + o11_3);

    // ---- bilinear per sample (weighted sum; same fmaf chain as before) ----
#define BILERP(s) \
    float4 v_##s;                                                               \
    v_##s.x = fmaf(t00_##s.x, w00_##s, fmaf(t01_##s.x, w01_##s,                 \
              fmaf(t10_##s.x, w10_##s, t11_##s.x * w11_##s)));                  \
    v_##s.y = fmaf(t00_##s.y, w00_##s, fmaf(t01_##s.y, w01_##s,                 \
              fmaf(t10_##s.y, w10_##s, t11_##s.y * w11_##s)));                  \
    v_##s.z = fmaf(t00_##s.z, w00_##s, fmaf(t01_##s.z, w01_##s,                 \
              fmaf(t10_##s.z, w10_##s, t11_##s.z * w11_##s)));                  \
    v_##s.w = fmaf(t00_##s.w, w00_##s, fmaf(t01_##s.w, w01_##s,                 \
              fmaf(t10_##s.w, w10_##s, t11_##s.w * w11_##s)));

    BILERP(0)
    BILERP(1)
    BILERP(2)
    BILERP(3)
#undef BILERP

    if (p < NPOS) {
        floatx4 m;
        m.x = fmaxf(fmaxf(v_0.x, v_1.x), fmaxf(v_2.x, v_3.x));
        m.y = fmaxf(fmaxf(v_0.y, v_1.y), fmaxf(v_2.y, v_3.y));
        m.z = fmaxf(fmaxf(v_0.z, v_1.z), fmaxf(v_2.z, v_3.z));
        m.w = fmaxf(fmaxf(v_0.w, v_1.w), fmaxf(v_2.w, v_3.w));
        // non-temporal: keep the 98MB output stream from evicting the slab
        __builtin_nontemporal_store(m,
            (floatx4*)(out + ((size_t)n * NPOS + p) * C_FM + slab * SLAB_C + q * 4));
    }
}

// ---------------------------------------------------------------------------
// Fallback (no workspace): direct all-channel kernel.
// ---------------------------------------------------------------------------
__global__ __launch_bounds__(256) void roi_pool_direct_kernel(
    const float* __restrict__ fm,
    const float* __restrict__ proposals,
    const int*   __restrict__ image_shape,
    float*       __restrict__ out,
    int N)
{
    __shared__ uint4  gO[NSAMP];
    __shared__ float4 gWf[NSAMP];

    const int n   = blockIdx.x;
    const int tid = threadIdx.x;

    if (tid < NSAMP) {
        const int s  = tid & 3;
        const int p  = tid >> 2;
        const int py = p / PH;
        const int px = p - py * PH;
        const int a  = s >> 1;
        const int b  = s & 1;

        const float himg = (float)image_shape[0];
        const float wimg = (float)image_shape[1];
        const float bx1 = proposals[n * 4 + 0] / wimg;
        const float by1 = proposals[n * 4 + 1] / himg;
        const float bx2 = proposals[n * 4 + 2] / wimg;
        const float by2 = proposals[n * 4 + 3] / himg;

        const float Hm1 = (float)(H_FM - 1);
        const float Wm1 = (float)(W_FM - 1);
        const float ystep = (by2 - by1) * Hm1 / (float)(CROP - 1);
        const float xstep = (bx2 - bx1) * Wm1 / (float)(CROP - 1);
        const float ys = by1 * Hm1 + (float)(2 * py + a) * ystep;
        const float xs = bx1 * Wm1 + (float)(2 * px + b) * xstep;

        const float y0f = floorf(ys);
        const float x0f = floorf(xs);
        const float ly  = ys - y0f;
        const float lx  = xs - x0f;
        int y0 = min(max((int)y0f, 0), H_FM - 1);
        int x0 = min(max((int)x0f, 0), W_FM - 1);
        const int dy = min(y0 + 1, H_FM - 1) - y0;
        const int dx = min(x0 + 1, W_FM - 1) - x0;
        const bool valid = (ys >= 0.0f) && (ys <= Hm1) &&
                           (xs >= 0.0f) && (xs <= Wm1);
        const float vf   = valid ? 1.0f : 0.0f;
        const float omlx = 1.0f - lx;
        const float omly = 1.0f - ly;

        float4 w;
        w.x = omlx * omly * vf;
        w.y = lx   * omly * vf;
        w.z = omlx * ly   * vf;
        w.w = lx   * ly   * vf;

        uint4 o;
        o.x = (uint32_t)(y0 * W_FM + x0) * PIXB;
        o.y = (uint32_t)dx * PIXB;
        o.z = (uint32_t)(dy * W_FM) * PIXB;
        o.w = 0u;
        gO[tid]  = o;
        gWf[tid] = w;
    }
    __syncthreads();

    const int wave = tid >> 6;
    const int lane = tid & 63;
    const uint32_t laneB = (uint32_t)lane * 16u;
    const char* fmB  = (const char*)fm;
    char*       outB = (char*)out + (size_t)n * (NPOS * PIXB);

    const int pbeg = (wave * NPOS) >> 2;
    const int pend = ((wave + 1) * NPOS) >> 2;

    for (int p = pbeg; p < pend; ++p) {
        float4 m;
        #pragma unroll
        for (int s = 0; s < 4; ++s) {
            const uint4  o = gO[p * 4 + s];
            const float4 w = gWf[p * 4 + s];
            const uint32_t o00 = o.x + laneB;
            const float4 t00 = *(const float4*)(fmB + o00);
            const float4 t01 = *(const float4*)(fmB + o00 + o.y);
            const float4 t10 = *(const float4*)(fmB + o00 + o.z);
            const float4 t11 = *(const float4*)(fmB + o00 + o.y + o.z);
            float4 v;
            v.x = fmaf(t00.x, w.x, fmaf(t01.x, w.y, fmaf(t10.x, w.z, t11.x * w.w)));
            v.y = fmaf(t00.y, w.x, fmaf(t01.y, w.y, fmaf(t10.y, w.z, t11.y * w.w)));
            v.z = fmaf(t00.z, w.x, fmaf(t01.z, w.y, fmaf(t10.z, w.z, t11.z * w.w)));
            v.w = fmaf(t00.w, w.x, fmaf(t01.w, w.y, fmaf(t10.w, w.z, t11.w * w.w)));
            if (s == 0) { m = v; }
            else {
                m.x = fmaxf(m.x, v.x); m.y = fmaxf(m.y, v.y);
                m.z = fmaxf(m.z, v.z); m.w = fmaxf(m.w, v.w);
            }
        }
        floatx4 mv;
        mv.x = m.x; mv.y = m.y; mv.z = m.z; mv.w = m.w;
        __builtin_nontemporal_store(mv,
            (floatx4*)(outB + (uint32_t)p * PIXB + laneB));
    }
}

extern "C" void kernel_launch(void* const* d_in, const int* in_sizes, int n_in,
                              void* d_out, int out_size, void* d_ws, size_t ws_size,
                              hipStream_t stream) {
    (void)n_in; (void)out_size;

    const float* fm        = (const float*)d_in[0];  // [1,200,304,256] f32
    const float* proposals = (const float*)d_in[1];  // [N,4] f32
    const int*   imshape   = (const int*)d_in[2];    // [2] i32
    float* out = (float*)d_out;                      // [N,7,7,256] f32

    const int N = in_sizes[1] / 4;                   // 2000
    const size_t need_slab = SLAB_BYTES;             // 62,259,200

    if (ws_size >= need_slab) {
        repack_kernel<<<NPIX / TP, 256, 0, stream>>>(fm, (float*)d_ws);
        roi_pool_fused_kernel<<<SLABS * N, 256, 0, stream>>>(
            (const float*)d_ws, proposals, imshape, out, N);
    } else {
        roi_pool_direct_kernel<<<N, 256, 0, stream>>>(
            fm, proposals, imshape, out, N);
    }
}